// Round 1
// 509.254 us; speedup vs baseline: 1.4610x; 1.4610x over previous
//
#include <hip/hip_runtime.h>
#include <cstdio>

#define D_ 256
#define LT 1024
#define LA 2048
#define NB 16
#define RR_ 64
#define NRT (NB*LT)   // 16384 text rows
#define NRA (NB*LA)   // 32768 audio rows

// logK u8 quantization: q = rint((1-cos)*124), logK_hat = q * DECQ
#define DECQ (-0.080645161f)

typedef short bf16x8 __attribute__((ext_vector_type(8)));
typedef float f32x4 __attribute__((ext_vector_type(4)));

__device__ __forceinline__ float gelu_f(float x) {
    return 0.5f * x * (1.0f + erff(x * 0.70710678118654752f));
}
__device__ __forceinline__ unsigned short f2bf(float f) {   // RNE
    union { float f; unsigned int i; } c; c.f = f;
    unsigned int x = c.i;
    return (unsigned short)((x + 0x7fffu + ((x >> 16) & 1u)) >> 16);
}

// ---------------- prep: all weight fp32->bf16 conversions in ONE launch ----------------
__global__ __launch_bounds__(256) void k_prep_all(
    const float* __restrict__ W_sh, const float* __restrict__ down_W,
    const float* __restrict__ up_W, const float* __restrict__ Wr1,
    unsigned short* __restrict__ Wb, unsigned short* __restrict__ dWb,
    unsigned short* __restrict__ uWb, unsigned short* __restrict__ Wr1b)
{
    int i = blockIdx.x * 256 + threadIdx.x;          // 0 .. 229375
    if (i < 65536) Wb[i] = f2bf(W_sh[i]);
    else if (i < 114688) { int j = i - 65536; dWb[j] = f2bf(down_W[j]); }
    else if (i < 163840) { int j = i - 114688; uWb[j] = f2bf(up_W[j]); }
    else { int j = i - 163840; int n = j >> 8, k = j & 255; Wr1b[j] = f2bf(Wr1[(long)n * 257 + 1 + k]); }
}

// ---------------- K1: LayerNorm + shared projection (MFMA) ----------------
__global__ __launch_bounds__(256) void k_lnproj_mfma(
    const float* __restrict__ X, const float* __restrict__ g, const float* __restrict__ bln,
    const unsigned short* __restrict__ Wb, const float* __restrict__ bsh,
    float* __restrict__ Pf, unsigned short* __restrict__ Nb)
{
    __shared__ short xb[64][264];
    __shared__ short Bs[256][40];
    int tid = threadIdx.x;
    long row0 = (long)blockIdx.x * 64;
    {
        int lane = tid & 31, rg = tid >> 5;
        float4 ga = *(const float4*)(g + lane * 8);
        float4 gb2 = *(const float4*)(g + lane * 8 + 4);
        float4 ba = *(const float4*)(bln + lane * 8);
        float4 bb2 = *(const float4*)(bln + lane * 8 + 4);
        for (int it = 0; it < 8; it++) {
            int r = it * 8 + rg;
            const float4* xp4 = (const float4*)(X + (row0 + r) * D_);
            float4 a = xp4[lane * 2], b = xp4[lane * 2 + 1];
            float s = a.x + a.y + a.z + a.w + b.x + b.y + b.z + b.w;
#pragma unroll
            for (int off = 16; off >= 1; off >>= 1) s += __shfl_xor(s, off);
            float mean = s * (1.0f / 256.0f);
            float q = (a.x - mean) * (a.x - mean) + (a.y - mean) * (a.y - mean)
                    + (a.z - mean) * (a.z - mean) + (a.w - mean) * (a.w - mean)
                    + (b.x - mean) * (b.x - mean) + (b.y - mean) * (b.y - mean)
                    + (b.z - mean) * (b.z - mean) + (b.w - mean) * (b.w - mean);
#pragma unroll
            for (int off = 16; off >= 1; off >>= 1) q += __shfl_xor(q, off);
            float ivar = rsqrtf(q * (1.0f / 256.0f) + 1e-5f);
            unsigned int u0 = f2bf((a.x - mean) * ivar * ga.x + ba.x);
            unsigned int u1 = f2bf((a.y - mean) * ivar * ga.y + ba.y);
            unsigned int u2 = f2bf((a.z - mean) * ivar * ga.z + ba.z);
            unsigned int u3 = f2bf((a.w - mean) * ivar * ga.w + ba.w);
            unsigned int u4 = f2bf((b.x - mean) * ivar * gb2.x + bb2.x);
            unsigned int u5 = f2bf((b.y - mean) * ivar * gb2.y + bb2.y);
            unsigned int u6 = f2bf((b.z - mean) * ivar * gb2.z + bb2.z);
            unsigned int u7 = f2bf((b.w - mean) * ivar * gb2.w + bb2.w);
            int4 pv;
            pv.x = (int)(u0 | (u1 << 16)); pv.y = (int)(u2 | (u3 << 16));
            pv.z = (int)(u4 | (u5 << 16)); pv.w = (int)(u6 | (u7 << 16));
            *(int4*)&xb[r][lane * 8] = pv;
        }
    }
    __syncthreads();
    int wid = tid >> 6, lane = tid & 63;
    int l15 = lane & 15, kq = lane >> 4;
    int m_local = wid * 16;
    f32x4 acc[16];
#pragma unroll
    for (int j = 0; j < 16; j++) acc[j] = (f32x4){0.f, 0.f, 0.f, 0.f};
    for (int kt = 0; kt < 8; kt++) {
        int k0 = kt * 32;
#pragma unroll
        for (int h = 0; h < 4; h++) {
            int idx = tid + 256 * h;
            int n = idx >> 2, qc = idx & 3;
            *(int4*)&Bs[n][qc * 8] = *(const int4*)(Wb + (long)n * D_ + k0 + qc * 8);
        }
        __syncthreads();
        bf16x8 af = *(const bf16x8*)&xb[m_local + l15][k0 + kq * 8];
#pragma unroll
        for (int j = 0; j < 16; j++) {
            bf16x8 bf = *(const bf16x8*)&Bs[j * 16 + l15][kq * 8];
            acc[j] = __builtin_amdgcn_mfma_f32_16x16x32_bf16(af, bf, acc[j], 0, 0, 0);
        }
        __syncthreads();
    }
#pragma unroll
    for (int j = 0; j < 16; j++) {
        float bv = bsh[j * 16 + l15];
#pragma unroll
        for (int r = 0; r < 4; r++) acc[j][r] += bv;
    }
    float sq[4] = {0.f, 0.f, 0.f, 0.f};
#pragma unroll
    for (int j = 0; j < 16; j++)
#pragma unroll
        for (int r = 0; r < 4; r++) sq[r] += acc[j][r] * acc[j][r];
#pragma unroll
    for (int off = 8; off >= 1; off >>= 1) {
#pragma unroll
        for (int r = 0; r < 4; r++) sq[r] += __shfl_xor(sq[r], off);
    }
    float rinv[4];
#pragma unroll
    for (int r = 0; r < 4; r++) rinv[r] = 1.0f / fmaxf(sqrtf(sq[r]), 1e-12f);
#pragma unroll
    for (int j = 0; j < 16; j++) {
        int col = j * 16 + l15;
#pragma unroll
        for (int r = 0; r < 4; r++) {
            long m = row0 + m_local + kq * 4 + r;
            if (Pf) Pf[m * D_ + col] = acc[j][r];
            Nb[m * D_ + col] = f2bf(acc[j][r] * rinv[r]);
        }
    }
}

// ---------------- K1b: Anb [b][n][d] -> ApbT [b][d][n] (LDS-tiled transpose) ----------------
__global__ __launch_bounds__(256) void k_transpose_bf(
    const unsigned short* __restrict__ Anb, unsigned short* __restrict__ ApbT)
{
    __shared__ short t[64][68];
    int b = blockIdx.x;              // batch fastest -> XCD pinned
    int n0 = blockIdx.y * 64;
    int d0 = blockIdx.z * 64;
    int tid = threadIdx.x;
#pragma unroll
    for (int h = 0; h < 2; h++) {
        int c = tid + 256 * h;       // 512 chunks
        int nr = c >> 3, ch = c & 7;
        *(int4*)&t[nr][ch * 8] = *(const int4*)(Anb + ((long)b * LA + n0 + nr) * D_ + d0 + ch * 8);
    }
    __syncthreads();
#pragma unroll
    for (int h = 0; h < 2; h++) {
        int c = tid + 256 * h;
        int d = c >> 3, nch = c & 7;
        unsigned short v[8];
#pragma unroll
        for (int k = 0; k < 8; k++) v[k] = (unsigned short)t[nch * 8 + k][d];
        int4 ov;
        ov.x = (int)((unsigned int)v[0] | ((unsigned int)v[1] << 16));
        ov.y = (int)((unsigned int)v[2] | ((unsigned int)v[3] << 16));
        ov.z = (int)((unsigned int)v[4] | ((unsigned int)v[5] << 16));
        ov.w = (int)((unsigned int)v[6] | ((unsigned int)v[7] << 16));
        *(int4*)(ApbT + ((long)b * D_ + d0 + d) * LA + n0 + nch * 8) = ov;
    }
}

// ---------------- K2: cost GEMM (MFMA bf16) -> logK u8 + transposed logK8T ----------------
__global__ __launch_bounds__(256) void k_cost_mfma(
    const unsigned short* __restrict__ Tnb, const unsigned short* __restrict__ Anb,
    unsigned char* __restrict__ logK8, unsigned char* __restrict__ logK8T)
{
    // As/Bs (24576 B) are dead after the K-loop; the u8 transpose tile
    // (128 rows x 144 B = 18432 B) reuses the same LDS -> no occupancy change.
    __shared__ short sm[2][128][48];
    short (*As)[48] = sm[0];
    short (*Bs)[48] = sm[1];
    unsigned char* tile = (unsigned char*)sm;
    int b = blockIdx.x;
    int m_blk = blockIdx.y * 128, n_blk = blockIdx.z * 128;
    int tid = threadIdx.x;
    int wid = tid >> 6, lane = tid & 63;
    int l15 = lane & 15, kq = lane >> 4;
    int wm0 = (wid >> 1) * 64, wn0 = (wid & 1) * 64;
    const unsigned short* Ab = Tnb + ((long)b * LT + m_blk) * D_;
    const unsigned short* Bb = Anb + ((long)b * LA + n_blk) * D_;
    f32x4 acc[4][4];
#pragma unroll
    for (int i = 0; i < 4; i++)
#pragma unroll
        for (int j = 0; j < 4; j++) acc[i][j] = (f32x4){0.f, 0.f, 0.f, 0.f};
    for (int kt = 0; kt < 8; kt++) {
        int k0 = kt * 32;
#pragma unroll
        for (int h = 0; h < 2; h++) {
            int idx = tid + 256 * h;
            int row = idx >> 2, ch = idx & 3;
            *(int4*)&As[row][ch * 8] = *(const int4*)(Ab + (long)row * D_ + k0 + ch * 8);
            *(int4*)&Bs[row][ch * 8] = *(const int4*)(Bb + (long)row * D_ + k0 + ch * 8);
        }
        __syncthreads();
        bf16x8 af[4], bfv[4];
#pragma unroll
        for (int i = 0; i < 4; i++) af[i] = *(const bf16x8*)&As[wm0 + i * 16 + l15][kq * 8];
#pragma unroll
        for (int j = 0; j < 4; j++) bfv[j] = *(const bf16x8*)&Bs[wn0 + j * 16 + l15][kq * 8];
#pragma unroll
        for (int i = 0; i < 4; i++)
#pragma unroll
            for (int j = 0; j < 4; j++)
                acc[i][j] = __builtin_amdgcn_mfma_f32_16x16x32_bf16(af[i], bfv[j], acc[i][j], 0, 0, 0);
        __syncthreads();
    }
    // quantize once: direct row-major byte stores + packed u32 into transpose tile
#pragma unroll
    for (int i = 0; i < 4; i++) {
#pragma unroll
        for (int j = 0; j < 4; j++) {
            int n = wn0 + j * 16 + l15;                       // n_local
            long base = ((long)b * LT + m_blk + wm0 + i * 16 + kq * 4) * (long)LA + n_blk + n;
            unsigned int pk = 0;
#pragma unroll
            for (int r = 0; r < 4; r++) {
                float q = rintf((1.0f - acc[i][j][r]) * 124.0f);
                q = fminf(fmaxf(q, 0.0f), 255.0f);
                unsigned int qb = (unsigned int)q;
                pk |= qb << (8 * r);
                logK8[base + (long)r * LA] = (unsigned char)qb;
            }
            *(unsigned int*)&tile[n * 144 + wm0 + i * 16 + kq * 4] = pk;
        }
    }
    __syncthreads();
#pragma unroll
    for (int h = 0; h < 4; h++) {
        int idx = tid + 256 * h;
        int row = idx >> 3, ch = idx & 7;                    // 128 n-rows x 8 int4 chunks
        int4 v = *(const int4*)&tile[row * 144 + ch * 16];
        *(int4*)(logK8T + ((long)b * LA + n_blk + row) * (long)LT + m_blk + ch * 16) = v;
    }
}

// ---------------- K3: row sum-exp -> lu (u8 logK, batch-fastest) ----------------
__global__ __launch_bounds__(256) void k_rowlse(
    const unsigned char* __restrict__ logK8, const float* __restrict__ lv,
    float* __restrict__ lu, int first)
{
    __shared__ float red[4];
    int b = blockIdx.x & 15;
    int m = blockIdx.x >> 4;
    long row = (long)b * LT + m;
    const unsigned char* p = logK8 + row * (long)LA;
    int tid = threadIdx.x;
    uint2 raw = *(const uint2*)(p + tid * 8);
    float lvv[8] = {0.f, 0.f, 0.f, 0.f, 0.f, 0.f, 0.f, 0.f};
    if (!first) {
        const float* lvp = lv + (long)b * LA;
        float4 l0 = *(const float4*)(lvp + tid * 8);
        float4 l1 = *(const float4*)(lvp + tid * 8 + 4);
        lvv[0] = l0.x; lvv[1] = l0.y; lvv[2] = l0.z; lvv[3] = l0.w;
        lvv[4] = l1.x; lvv[5] = l1.y; lvv[6] = l1.z; lvv[7] = l1.w;
    }
    unsigned int w0 = raw.x, w1 = raw.y;
    float s = 0.f;
    s += __expf((float)(w0 & 0xffu) * DECQ + lvv[0]);
    s += __expf((float)((w0 >> 8) & 0xffu) * DECQ + lvv[1]);
    s += __expf((float)((w0 >> 16) & 0xffu) * DECQ + lvv[2]);
    s += __expf((float)(w0 >> 24) * DECQ + lvv[3]);
    s += __expf((float)(w1 & 0xffu) * DECQ + lvv[4]);
    s += __expf((float)((w1 >> 8) & 0xffu) * DECQ + lvv[5]);
    s += __expf((float)((w1 >> 16) & 0xffu) * DECQ + lvv[6]);
    s += __expf((float)(w1 >> 24) * DECQ + lvv[7]);
#pragma unroll
    for (int off = 32; off >= 1; off >>= 1) s += __shfl_xor(s, off);
    if ((tid & 63) == 0) red[tid >> 6] = s;
    __syncthreads();
    if (tid == 0) lu[row] = -6.9314718055994531f - __logf(red[0] + red[1] + red[2] + red[3]);
}

// ---------------- K4: col sum-exp over TRANSPOSED logK -> lv (coalesced, high-occ) ----------------
// grid (NB, LA/8): 4096 blocks; 32 threads per n-column, 8 columns per block.
__global__ __launch_bounds__(256) void k_collse_t(
    const unsigned char* __restrict__ logK8T, const float* __restrict__ lu, float* __restrict__ lv)
{
    int b = blockIdx.x;
    int n = blockIdx.y * 8 + (threadIdx.x >> 5);
    int lr = threadIdx.x & 31;
    const unsigned char* p = logK8T + ((long)b * LA + n) * (long)LT;
    const float* lup = lu + (long)b * LT;
    float s = 0.f;
#pragma unroll
    for (int q = 0; q < 8; q++) {
        int m = q * 128 + lr * 4;
        unsigned int w = *(const unsigned int*)(p + m);
        float4 l4 = *(const float4*)(lup + m);
        s += __expf((float)(w & 0xffu) * DECQ + l4.x);
        s += __expf((float)((w >> 8) & 0xffu) * DECQ + l4.y);
        s += __expf((float)((w >> 16) & 0xffu) * DECQ + l4.z);
        s += __expf((float)(w >> 24) * DECQ + l4.w);
    }
#pragma unroll
    for (int off = 16; off >= 1; off >>= 1) s += __shfl_xor(s, off);
    if (lr == 0) lv[(long)b * LA + n] = -7.6246189861593985f - __logf(s);
}

// ---------------- K5: A_al = pi @ Ap (MFMA; u8 logK, K-split x2, batch-fastest) ----------------
__global__ __launch_bounds__(256) void k_pi_mfma(
    const unsigned char* __restrict__ logK8, const unsigned short* __restrict__ ApbT,
    const float* __restrict__ lu, const float* __restrict__ lv, float* __restrict__ Apart)
{
    __shared__ short As[64][48];
    __shared__ short Bs[256][48];
    __shared__ float lv_s[1024];
    __shared__ float lu_s[64];
    int b = blockIdx.x;
    int kh = blockIdx.y;
    int m_blk = blockIdx.z * 64;
    int nbase = kh * 1024;
    int tid = threadIdx.x;
    for (int i = tid; i < 1024; i += 256) lv_s[i] = lv[(long)b * LA + nbase + i];
    if (tid < 64) lu_s[tid] = lu[(long)b * LT + m_blk + tid];
    __syncthreads();
    int wid = tid >> 6, lane = tid & 63;
    int l15 = lane & 15, kq = lane >> 4;
    int wm0 = (wid & 1) * 32, wd0 = (wid >> 1) * 128;
    f32x4 acc[2][8];
#pragma unroll
    for (int i = 0; i < 2; i++)
#pragma unroll
        for (int j = 0; j < 8; j++) acc[i][j] = (f32x4){0.f, 0.f, 0.f, 0.f};
    const unsigned char* Kbase = logK8 + ((long)b * LT + m_blk) * (long)LA + nbase;
    const unsigned short* Bbase = ApbT + (long)b * D_ * (long)LA + nbase;
    int arow = tid >> 2, ac8 = (tid & 3) * 8;
    for (int kt = 0; kt < 32; kt++) {
        int n0 = kt * 32;
        {
            uint2 raw = *(const uint2*)(Kbase + (long)arow * LA + n0 + ac8);
            float lum = lu_s[arow];
            const float* lvp = &lv_s[n0 + ac8];
            unsigned int w0 = raw.x, w1 = raw.y;
            unsigned int o0 = f2bf(__expf((float)(w0 & 0xffu) * DECQ + lum + lvp[0]));
            unsigned int o1 = f2bf(__expf((float)((w0 >> 8) & 0xffu) * DECQ + lum + lvp[1]));
            unsigned int o2 = f2bf(__expf((float)((w0 >> 16) & 0xffu) * DECQ + lum + lvp[2]));
            unsigned int o3 = f2bf(__expf((float)(w0 >> 24) * DECQ + lum + lvp[3]));
            unsigned int o4 = f2bf(__expf((float)(w1 & 0xffu) * DECQ + lum + lvp[4]));
            unsigned int o5 = f2bf(__expf((float)((w1 >> 8) & 0xffu) * DECQ + lum + lvp[5]));
            unsigned int o6 = f2bf(__expf((float)((w1 >> 16) & 0xffu) * DECQ + lum + lvp[6]));
            unsigned int o7 = f2bf(__expf((float)(w1 >> 24) * DECQ + lum + lvp[7]));
            int4 ov;
            ov.x = (int)(o0 | (o1 << 16)); ov.y = (int)(o2 | (o3 << 16));
            ov.z = (int)(o4 | (o5 << 16)); ov.w = (int)(o6 | (o7 << 16));
            *(int4*)&As[arow][ac8] = ov;
        }
#pragma unroll
        for (int h = 0; h < 4; h++) {
            int idx = tid + 256 * h;
            int row = idx >> 2, ch = idx & 3;
            *(int4*)&Bs[row][ch * 8] = *(const int4*)(Bbase + (long)row * LA + n0 + ch * 8);
        }
        __syncthreads();
        bf16x8 af[2], bfv[8];
        af[0] = *(const bf16x8*)&As[wm0 + l15][kq * 8];
        af[1] = *(const bf16x8*)&As[wm0 + 16 + l15][kq * 8];
#pragma unroll
        for (int j = 0; j < 8; j++) bfv[j] = *(const bf16x8*)&Bs[wd0 + j * 16 + l15][kq * 8];
#pragma unroll
        for (int i = 0; i < 2; i++)
#pragma unroll
            for (int j = 0; j < 8; j++)
                acc[i][j] = __builtin_amdgcn_mfma_f32_16x16x32_bf16(af[i], bfv[j], acc[i][j], 0, 0, 0);
        __syncthreads();
    }
    float* dst = Apart + (long)kh * (NB * (long)LT * D_);
#pragma unroll
    for (int i = 0; i < 2; i++) {
#pragma unroll
        for (int r = 0; r < 4; r++) {
            int m = m_blk + wm0 + i * 16 + kq * 4 + r;
            long obase = ((long)b * LT + m) * D_;
#pragma unroll
            for (int j = 0; j < 8; j++)
                dst[obase + wd0 + j * 16 + l15] = acc[i][j][r];
        }
    }
}

// ---------------- K6: combine K-halves, S, resid (batch-fastest) ----------------
__global__ __launch_bounds__(256) void k_sresid(
    const float* __restrict__ Tp, const float* __restrict__ Apart,
    float* __restrict__ resid, unsigned short* __restrict__ residb, float* __restrict__ S)
{
    __shared__ float red[4];
    int b = blockIdx.x & 15;
    int m = blockIdx.x >> 4;
    long row = (long)b * LT + m;
    int tid = threadIdx.x;
    long idx = row * D_ + tid;
    float t = Tp[idx];
    float a = Apart[idx] + Apart[idx + (long)NB * LT * D_];
    float rr = fabsf(t - a);
    resid[idx] = rr;
    residb[idx] = f2bf(rr);
    float p = t * a;
#pragma unroll
    for (int off = 32; off >= 1; off >>= 1) p += __shfl_xor(p, off);
    if ((tid & 63) == 0) red[tid >> 6] = p;
    __syncthreads();
    if (tid == 0) S[row] = red[0] + red[1] + red[2] + red[3];
}

// ---------------- K7: router fused, col-split waves: 16 rows/block, grid NRT/16 ----------------
// Each of the 4 waves owns 64 output cols of the same 16 rows; partial logits
// are combined across waves in LDS. 1024 blocks -> 4 blocks/CU, 16 waves/CU.
__global__ __launch_bounds__(256) void k_router_fused(
    const unsigned short* __restrict__ residb, const unsigned short* __restrict__ Wr1b,
    const float* __restrict__ Wr1, const float* __restrict__ br1,
    const float* __restrict__ S, const float* __restrict__ Wr2,
    const float* __restrict__ br2, float* __restrict__ G)
{
    __shared__ short xb[16][264];
    __shared__ short Bs[256][40];
    __shared__ float red[4][3][16];
    int tid = threadIdx.x;
    long row0 = (long)blockIdx.x * 16;
#pragma unroll
    for (int h = 0; h < 2; h++) {
        int idx = tid + 256 * h;
        int row = idx >> 5, ch = idx & 31;
        *(int4*)&xb[row][ch * 8] = *(const int4*)(residb + (row0 + row) * D_ + ch * 8);
    }
    __syncthreads();
    int wid = tid >> 6, lane = tid & 63;
    int l15 = lane & 15, kq = lane >> 4;
    f32x4 acc[4];
#pragma unroll
    for (int j = 0; j < 4; j++) acc[j] = (f32x4){0.f, 0.f, 0.f, 0.f};
    for (int kt = 0; kt < 8; kt++) {
        int k0 = kt * 32;
#pragma unroll
        for (int h = 0; h < 4; h++) {
            int idx = tid + 256 * h;
            int n = idx >> 2, qc = idx & 3;
            *(int4*)&Bs[n][qc * 8] = *(const int4*)(Wr1b + (long)n * D_ + k0 + qc * 8);
        }
        __syncthreads();
        bf16x8 af = *(const bf16x8*)&xb[l15][k0 + kq * 8];
#pragma unroll
        for (int j = 0; j < 4; j++) {
            bf16x8 bf = *(const bf16x8*)&Bs[wid * 64 + j * 16 + l15][kq * 8];
            acc[j] = __builtin_amdgcn_mfma_f32_16x16x32_bf16(af, bf, acc[j], 0, 0, 0);
        }
        __syncthreads();
    }
    float sv[4];
#pragma unroll
    for (int r = 0; r < 4; r++) sv[r] = S[row0 + kq * 4 + r];
    float le[3][4] = {};
#pragma unroll
    for (int j = 0; j < 4; j++) {
        int col = wid * 64 + j * 16 + l15;
        float w0 = Wr1[(long)col * 257];
        float bv = br1[col];
        float w2a = Wr2[col], w2b = Wr2[256 + col], w2c = Wr2[512 + col];
#pragma unroll
        for (int r = 0; r < 4; r++) {
            float hv = gelu_f(acc[j][r] + sv[r] * w0 + bv);
            le[0][r] += hv * w2a;
            le[1][r] += hv * w2b;
            le[2][r] += hv * w2c;
        }
    }
#pragma unroll
    for (int off = 8; off >= 1; off >>= 1)
#pragma unroll
        for (int e = 0; e < 3; e++)
#pragma unroll
            for (int r = 0; r < 4; r++) le[e][r] += __shfl_xor(le[e][r], off);
    if (l15 == 0) {
#pragma unroll
        for (int e = 0; e < 3; e++)
#pragma unroll
            for (int r = 0; r < 4; r++) red[wid][e][kq * 4 + r] = le[e][r];
    }
    __syncthreads();
    if (tid < 16) {
        float L0 = red[0][0][tid] + red[1][0][tid] + red[2][0][tid] + red[3][0][tid] + br2[0];
        float L1 = red[0][1][tid] + red[1][1][tid] + red[2][1][tid] + red[3][1][tid] + br2[1];
        float L2 = red[0][2][tid] + red[1][2][tid] + red[2][2][tid] + red[3][2][tid] + br2[2];
        float mx = fmaxf(L0, fmaxf(L1, L2));
        float e0 = __expf(L0 - mx), e1 = __expf(L1 - mx), e2 = __expf(L2 - mx);
        float inv = 1.0f / (e0 + e1 + e2);
        long m = row0 + tid;
        G[m] = e0 * inv; G[NRT + m] = e1 * inv; G[2 * NRT + m] = e2 * inv;
    }
}

// ---------------- K8a: h[e] = gelu(residb @ down_W[e]^T + down_b[e]) ----------------
__global__ __launch_bounds__(256) void k_down_mfma(
    const unsigned short* __restrict__ residb, const unsigned short* __restrict__ dWb,
    const float* __restrict__ db, float* __restrict__ hall)
{
    __shared__ short xb[64][264];
    __shared__ short Bs[64][40];
    int tid = threadIdx.x;
    int e = blockIdx.y;
    int b = blockIdx.x & 15;
    int mseg = blockIdx.x >> 4;
    long row0 = (long)b * LT + mseg * 64;
    const unsigned short* dWe = dWb + (long)e * RR_ * D_;
    float* h = hall + (long)e * NRT * RR_;
#pragma unroll
    for (int hh = 0; hh < 8; hh++) {
        int idx = tid + 256 * hh;
        int row = idx >> 5, ch = idx & 31;
        *(int4*)&xb[row][ch * 8] = *(const int4*)(residb + (row0 + row) * D_ + ch * 8);
    }
    __syncthreads();
    int wid = tid >> 6, lane = tid & 63;
    int l15 = lane & 15, kq = lane >> 4;
    int m_local = wid * 16;
    f32x4 acc[4];
#pragma unroll
    for (int j = 0; j < 4; j++) acc[j] = (f32x4){0.f, 0.f, 0.f, 0.f};
    for (int kt = 0; kt < 8; kt++) {
        int k0 = kt * 32;
        {
            int n = tid >> 2, qc = tid & 3;
            *(int4*)&Bs[n][qc * 8] = *(const int4*)(dWe + (long)n * D_ + k0 + qc * 8);
        }
        __syncthreads();
        bf16x8 af = *(const bf16x8*)&xb[m_local + l15][k0 + kq * 8];
#pragma unroll
        for (int j = 0; j < 4; j++) {
            bf16x8 bf = *(const bf16x8*)&Bs[j * 16 + l15][kq * 8];
            acc[j] = __builtin_amdgcn_mfma_f32_16x16x32_bf16(af, bf, acc[j], 0, 0, 0);
        }
        __syncthreads();
    }
#pragma unroll
    for (int j = 0; j < 4; j++) {
        int col = j * 16 + l15;
        float bv = db[e * RR_ + col];
#pragma unroll
        for (int r = 0; r < 4; r++) {
            long m = row0 + m_local + kq * 4 + r;
            h[m * RR_ + col] = gelu_f(acc[j][r] + bv);
        }
    }
}

// ---------------- K8b: depth-conv, all 3 experts in one launch -> bf16 ----------------
__global__ __launch_bounds__(256) void k_conv_all(
    const float* __restrict__ hall, const float* __restrict__ cw1,
    const float* __restrict__ cw3, const float* __restrict__ cw5,
    const float* __restrict__ conv_b, unsigned short* __restrict__ hcbb)
{
    __shared__ float hs[68][68];
    __shared__ float wt[64][64];
    int e = blockIdx.y;
    const float* w = (e == 0) ? cw1 : ((e == 1) ? cw3 : cw5);
    int ksz = (e == 0) ? 1 : ((e == 1) ? 3 : 5);
    const float* h = hall + (long)e * NRT * RR_;
    unsigned short* hcb = hcbb + (long)e * NRT * RR_;
    const float* cb = conv_b + e * 64;
    int b = blockIdx.x & 15;
    int m0 = (blockIdx.x >> 4) * 64;
    int tid = threadIdx.x;
    int pad = (ksz - 1) >> 1;
    for (int idx = tid; idx < 68 * 16; idx += 256) {
        int mr = idx >> 4, i4 = idx & 15;
        int mm = m0 - 2 + mr;
        float4 vv = { 0.f, 0.f, 0.f, 0.f };
        if (mm >= 0 && mm < LT) vv = *(const float4*)(h + ((long)b * LT + mm) * RR_ + i4 * 4);
        *(float4*)&hs[mr][i4 * 4] = vv;
    }
    int tx = tid & 15, ty = tid >> 4;
    float acc[4][4] = {};
    for (int t = 0; t < ksz; t++) {
        __syncthreads();
        for (int idx = tid; idx < 4096; idx += 256) {
            int i = idx & 63, j = idx >> 6;
            wt[i][j] = w[(long)j * RR_ * ksz + i * ksz + t];
        }
        __syncthreads();
        int roff = ty * 4 + 2 + t - pad;
        for (int i4 = 0; i4 < 16; i4++) {
            float4 h0 = *(const float4*)&hs[roff + 0][i4 * 4];
            float4 h1 = *(const float4*)&hs[roff + 1][i4 * 4];
            float4 h2 = *(const float4*)&hs[roff + 2][i4 * 4];
            float4 h3 = *(const float4*)&hs[roff + 3][i4 * 4];
            float hh[4][4] = { { h0.x, h0.y, h0.z, h0.w }, { h1.x, h1.y, h1.z, h1.w },
                               { h2.x, h2.y, h2.z, h2.w }, { h3.x, h3.y, h3.z, h3.w } };
#pragma unroll
            for (int s = 0; s < 4; s++) {
                float4 wv = *(const float4*)&wt[i4 * 4 + s][tx * 4];
#pragma unroll
                for (int r = 0; r < 4; r++) {
                    acc[r][0] += hh[r][s] * wv.x;
                    acc[r][1] += hh[r][s] * wv.y;
                    acc[r][2] += hh[r][s] * wv.z;
                    acc[r][3] += hh[r][s] * wv.w;
                }
            }
        }
    }
    float4 bb = *(const float4*)(cb + tx * 4);
#pragma unroll
    for (int r = 0; r < 4; r++) {
        long m = (long)b * LT + m0 + ty * 4 + r;
        unsigned long long pv =
              (unsigned long long)f2bf(gelu_f(acc[r][0] + bb.x))
            | ((unsigned long long)f2bf(gelu_f(acc[r][1] + bb.y)) << 16)
            | ((unsigned long long)f2bf(gelu_f(acc[r][2] + bb.z)) << 32)
            | ((unsigned long long)f2bf(gelu_f(acc[r][3] + bb.w)) << 48);
        *(unsigned long long*)(hcb + m * RR_ + tx * 4) = pv;
    }
}

// ---------------- K8c: all 3 experts: up-proj + resid + LN + gated sum, ONE out write ----------------
__global__ __launch_bounds__(256) void k_up3(
    const unsigned short* __restrict__ hcbb, const unsigned short* __restrict__ uWb,
    const float* __restrict__ up_b, const float* __restrict__ resid,
    const float* __restrict__ en_g, const float* __restrict__ en_b,
    const float* __restrict__ G, float* __restrict__ out)
{
    __shared__ short hs[64][88];
    __shared__ short Bs[256][40];
    int tid = threadIdx.x;
    int b = blockIdx.x & 15;
    int mseg = blockIdx.x >> 4;
    long row0 = (long)b * LT + mseg * 64;
    int wid = tid >> 6, lane = tid & 63;
    int l15 = lane & 15, kq = lane >> 4;
    int m_local = wid * 16;
    long mrow[4];
#pragma unroll
    for (int r = 0; r < 4; r++) mrow[r] = row0 + m_local + kq * 4 + r;
    f32x4 outacc[16];
#pragma unroll
    for (int j = 0; j < 16; j++) outacc[j] = (f32x4){0.f, 0.f, 0.f, 0.f};
    for (int e = 0; e < 3; e++) {
        __syncthreads();   // prior expert's LDS readers done
        const unsigned short* hcb = hcbb + (long)e * NRT * RR_;
        const unsigned short* uWe = uWb + (long)e * 16384;
#pragma unroll
        for (int hh = 0; hh < 2; hh++) {
            int idx = tid + 256 * hh;
            int row = idx >> 3, ch = idx & 7;
            *(int4*)&hs[row][ch * 8] = *(const int4*)(hcb + (row0 + row) * RR_ + ch * 8);
        }
        f32x4 acc[16];
#pragma unroll
        for (int j = 0; j < 16; j++) acc[j] = (f32x4){0.f, 0.f, 0.f, 0.f};
        for (int kt = 0; kt < 2; kt++) {
            int k0 = kt * 32;
#pragma unroll
            for (int hh = 0; hh < 4; hh++) {
                int idx = tid + 256 * hh;
                int n = idx >> 2, qc = idx & 3;
                *(int4*)&Bs[n][qc * 8] = *(const int4*)(uWe + (long)n * RR_ + k0 + qc * 8);
            }
            __syncthreads();
            bf16x8 af = *(const bf16x8*)&hs[m_local + l15][k0 + kq * 8];
#pragma unroll
            for (int j = 0; j < 16; j++) {
                bf16x8 bf = *(const bf16x8*)&Bs[j * 16 + l15][kq * 8];
                acc[j] = __builtin_amdgcn_mfma_f32_16x16x32_bf16(af, bf, acc[j], 0, 0, 0);
            }
            __syncthreads();
        }
        const float* ub = up_b + e * 256;
#pragma unroll
        for (int j = 0; j < 16; j++) {
            int col = j * 16 + l15;
            float bv = ub[col];
#pragma unroll
            for (int r = 0; r < 4; r++)
                acc[j][r] += bv + resid[mrow[r] * D_ + col];
        }
        float s[4] = {0.f, 0.f, 0.f, 0.f};
#pragma unroll
        for (int j = 0; j < 16; j++)
#pragma unroll
            for (int r = 0; r < 4; r++) s[r] += acc[j][r];
#pragma unroll
        for (int off = 8; off >= 1; off >>= 1)
#pragma unroll
            for (int r = 0; r < 4; r++) s[r] += __shfl_xor(s[r], off);
        float mn[4];
#pragma unroll
        for (int r = 0; r < 4; r++) mn[r] = s[r] * (1.0f / 256.0f);
        float q[4] = {0.f, 0.f, 0.f, 0.f};
#pragma unroll
        for (int j = 0; j < 16; j++)
#pragma unroll
            for (int r = 0; r < 4; r++) { float d = acc[j][r] - mn[r]; q[r] += d * d; }
#pragma unroll
        for (int off = 8; off >= 1; off >>= 1)
#pragma unroll
            for (int r = 0; r < 4; r++) q[r] += __shfl_xor(q[r], off);
        float iv[4], gv[4];
#pragma unroll
        for (int r = 0; r < 4; r++) {
            iv[r] = rsqrtf(q[r] * (1.0f / 256.0f) + 1e-5f);
            gv[r] = G[(long)e * NRT + mrow[r]];
        }
        const float* eg = en_g + e * 256;
        const float* eb = en_b + e * 256;
#pragma unroll
        for (int j = 0; j < 16; j++) {
            int col = j * 16 + l15;
            float egc = eg[col], ebc = eb[col];
#pragma unroll
            for (int r = 0; r < 4; r++)
                outacc[j][r] += gv[r] * ((acc[j][r] - mn[r]) * iv[r] * egc + ebc);
        }
    }
#pragma unroll
    for (int j = 0; j < 16; j++) {
        int col = j * 16 + l15;
#pragma unroll
        for (int r = 0; r < 4; r++)
            out[mrow[r] * D_ + col] = outacc[j][r];
    }
}

extern "C" void kernel_launch(void* const* d_in, const int* in_sizes, int n_in,
                              void* d_out, int out_size, void* d_ws, size_t ws_size,
                              hipStream_t stream)
{
    const float* text   = (const float*)d_in[0];
    const float* audio  = (const float*)d_in[1];
    const float* ln_g   = (const float*)d_in[2];
    const float* ln_b   = (const float*)d_in[3];
    const float* W_sh   = (const float*)d_in[4];
    const float* b_sh   = (const float*)d_in[5];
    const float* Wr1    = (const float*)d_in[6];
    const float* br1    = (const float*)d_in[7];
    const float* Wr2    = (const float*)d_in[8];
    const float* br2    = (const float*)d_in[9];
    const float* down_W = (const float*)d_in[10];
    const float* down_b = (const float*)d_in[11];
    const float* cw1    = (const float*)d_in[12];
    const float* cw3    = (const float*)d_in[13];
    const float* cw5    = (const float*)d_in[14];
    const float* conv_b = (const float*)d_in[15];
    const float* up_W   = (const float*)d_in[16];
    const float* up_b   = (const float*)d_in[17];
    const float* en_g   = (const float*)d_in[18];
    const float* en_b   = (const float*)d_in[19];

    float* ws = (float*)d_ws;
    float*          Tp    = ws;                               // 4,194,304 f
    unsigned short* Tnb   = (unsigned short*)(ws + 4194304);  // 2,097,152 f
    unsigned short* Anb   = (unsigned short*)(ws + 6291456);  // 4,194,304 f
    unsigned short* ApbT  = (unsigned short*)(ws + 10485760); // 4,194,304 f
    unsigned char*  logK8 = (unsigned char*)(ws + 14680064);  // 8,388,608 f (33.5 MB u8)
    float*          Apart = ws + 23068672;                    // 2 x 4,194,304 f
    float*          resid = ws + 31457280;                    // 4,194,304 f
    unsigned short* residb= (unsigned short*)(ws + 35651584); // 2,097,152 f
    float*          lu    = ws + 37748736;                    // 16,384
    float*          lv    = ws + 37765120;                    // 32,768
    float*          Sb    = ws + 37797888;                    // 16,384
    float*          Gb    = ws + 37814272;                    // 49,152
    unsigned short* Wb    = (unsigned short*)(ws + 37863424); // 32,768 f
    unsigned short* dWb   = (unsigned short*)(ws + 37896192); // 24,576 f
    unsigned short* uWb   = (unsigned short*)(ws + 37920768); // 24,576 f
    unsigned short* Wr1b  = (unsigned short*)(ws + 37945344); // 32,768 f
    size_t need_bytes = (size_t)37978112 * 4;
    if (ws_size < need_bytes) {
        fprintf(stderr, "kernel_launch: ws_size %zu < needed %zu\n", ws_size, need_bytes);
        return;
    }
    // aliases in logK8 region (dead after k_pi_mfma):
    float*          hall = ws + 14680064;                     // 3,145,728 f
    unsigned short* hcbb = (unsigned short*)(ws + 17825792);  // 1,572,864 f
    // logK8T aliases Apart (33,554,432 B each): written by k_cost_mfma, read by
    // k_collse_t x10, dead before k_pi_mfma writes Apart (stream-ordered).
    unsigned char*  logK8T = (unsigned char*)(ws + 23068672);

    k_prep_all<<<896, 256, 0, stream>>>(W_sh, down_W, up_W, Wr1, Wb, dWb, uWb, Wr1b);
    k_lnproj_mfma<<<NRT / 64, 256, 0, stream>>>(text, ln_g, ln_b, Wb, b_sh, Tp, Tnb);
    k_lnproj_mfma<<<NRA / 64, 256, 0, stream>>>(audio, ln_g, ln_b, Wb, b_sh, nullptr, Anb);
    k_transpose_bf<<<dim3(NB, LA / 64, D_ / 64), 256, 0, stream>>>(Anb, ApbT);
    k_cost_mfma<<<dim3(NB, LT / 128, LA / 128), 256, 0, stream>>>(Tnb, Anb, logK8, logK8T);
    for (int it = 0; it < 10; it++) {
        k_rowlse<<<NRT, 256, 0, stream>>>(logK8, lv, lu, it == 0 ? 1 : 0);
        k_collse_t<<<dim3(NB, LA / 8), 256, 0, stream>>>(logK8T, lu, lv);
    }
    k_pi_mfma<<<dim3(NB, 2, LT / 64), 256, 0, stream>>>(logK8, ApbT, lu, lv, Apart);
    k_sresid<<<NRT, 256, 0, stream>>>(Tp, Apart, resid, residb, Sb);
    k_router_fused<<<NRT / 16, 256, 0, stream>>>(residb, Wr1b, Wr1, br1, Sb, Wr2, br2, Gb);
    k_down_mfma<<<dim3(NRT / 64, 3), 256, 0, stream>>>(residb, dWb, down_b, hall);
    k_conv_all<<<dim3(NRT / 64, 3), 256, 0, stream>>>(hall, cw1, cw3, cw5, conv_b, hcbb);
    k_up3<<<NRT / 64, 256, 0, stream>>>(hcbb, uWb, up_b, resid, en_g, en_b, Gb, (float*)d_out);
}